// Round 3
// baseline (19.396 us; speedup 1.0000x reference)
//
#include <hip/hip_runtime.h>

#define LOOKBACK 8
#define HID 32
#define TB 256
#define TPT 64          // t's per block
#define NR  (TPT + LOOKBACK)   // 72 K rows per block
#define KST 36          // floats; 144B row stride (16B aligned, spreads banks)
#define EPS 1e-6f

// d_ws float layout (written by prep_kernel every call)
#define WS_AQ  0     // [4][32]  A_Q
#define WS_CQ  128   // [32]     c_Q
#define WS_AK  160   // [4][32]  A_K
#define WS_CK  288   // [32]     c_K
#define WS_AVW 320   // [4]      a_vw
#define WS_CVW 324   // scalar   c_vw

__global__ __launch_bounds__(64) void prep_kernel(
    const float* __restrict__ sb, const float* __restrict__ vs,
    const float* __restrict__ vb, const float* __restrict__ bw,
    const float* __restrict__ WQ, const float* __restrict__ WK,
    const float* __restrict__ WV, const float* __restrict__ wh,
    float* __restrict__ P)
{
    const int h = threadIdx.x;
    if (h >= HID) return;

    float wq[11], wk[11], wv[11];
#pragma unroll
    for (int j = 0; j < 11; ++j) {
        wq[j] = WQ[j * HID + h];
        wk[j] = WK[j * HID + h];
        wv[j] = WV[j * HID + h];
    }
    float b0 = bw[0], b1 = bw[1], b2 = bw[2], b3 = bw[3], b4 = bw[4], b5 = bw[5];
    float v0 = vs[0], v1 = vs[1], v2 = vs[2], v3 = vs[3];
    float u0 = vb[0], u1 = vb[1], u2 = vb[2], u3 = vb[3];
    float s0 = 1.0f + sb[0];

    // A[d][h]: x_d coefficient.  BIV_I=[0,0,0,1,1,2], BIV_J=[1,2,3,2,3,3]
    float aq[4], ak[4], av[4];
    aq[0] = v0*wq[1] + b0*wq[5] + b1*wq[6] + b2*wq[7];
    aq[1] = v1*wq[2] - b0*wq[5] + b3*wq[8] + b4*wq[9];
    aq[2] = v2*wq[3] - b1*wq[6] - b3*wq[8] + b5*wq[10];
    aq[3] = v3*wq[4] - b2*wq[7] - b4*wq[9] - b5*wq[10];
    ak[0] = v0*wk[1] + b0*wk[5] + b1*wk[6] + b2*wk[7];
    ak[1] = v1*wk[2] - b0*wk[5] + b3*wk[8] + b4*wk[9];
    ak[2] = v2*wk[3] - b1*wk[6] - b3*wk[8] + b5*wk[10];
    ak[3] = v3*wk[4] - b2*wk[7] - b4*wk[9] - b5*wk[10];
    av[0] = v0*wv[1] + b0*wv[5] + b1*wv[6] + b2*wv[7];
    av[1] = v1*wv[2] - b0*wv[5] + b3*wv[8] + b4*wv[9];
    av[2] = v2*wv[3] - b1*wv[6] - b3*wv[8] + b5*wv[10];
    av[3] = v3*wv[4] - b2*wv[7] - b4*wv[9] - b5*wv[10];

    float cq = s0*wq[0] + u0*wq[1] + u1*wq[2] + u2*wq[3] + u3*wq[4];
    float ck = s0*wk[0] + u0*wk[1] + u1*wk[2] + u2*wk[3] + u3*wk[4];
    float cv = s0*wv[0] + u0*wv[1] + u1*wv[2] + u2*wv[3] + u3*wv[4];

#pragma unroll
    for (int d = 0; d < 4; ++d) {
        P[WS_AQ + d * HID + h] = aq[d];
        P[WS_AK + d * HID + h] = ak[d];
    }
    P[WS_CQ + h] = cq;
    P[WS_CK + h] = ck;

    // a_vw[d] = sum_h av[d]*wh[h];  c_vw = sum_h cv*wh[h]
    const float w = wh[h];
    float r[5] = { av[0]*w, av[1]*w, av[2]*w, av[3]*w, cv*w };
#pragma unroll
    for (int off = 16; off > 0; off >>= 1) {
#pragma unroll
        for (int i = 0; i < 5; ++i) r[i] += __shfl_down(r[i], off, 32);
    }
    if (h == 0) {
        P[WS_AVW + 0] = r[0]; P[WS_AVW + 1] = r[1];
        P[WS_AVW + 2] = r[2]; P[WS_AVW + 3] = r[3];
        P[WS_CVW]     = r[4];
    }
}

__device__ __forceinline__ float phi1(float z) {
    return (z >= 0.0f ? z : 0.01f * z) + 1.0f;
}

__global__ __launch_bounds__(TB) void ga_main(
    const float* __restrict__ x,       // (B, L, 4)
    const float* __restrict__ P,       // collapsed params
    const float* __restrict__ b_head,
    float* __restrict__ out,           // pred (B*T) then weights (B*T*8)
    int B, int L)
{
    const int T   = L - LOOKBACK;
    const int bb  = blockIdx.y;
    const int t0  = blockIdx.x * TPT;
    const int tid = threadIdx.x;
    const int t_local = tid >> 2;
    const int hs      = tid & 3;       // 8-channel group [hs*8, hs*8+8)

    __shared__ float sK[NR * KST];
    __shared__ float sVW[NR];

    // ---- prefetch this thread's query x early (hides under phase A) ----
    const int t = t0 + t_local;
    const bool valid = (t < T);
    const float4 xq = *reinterpret_cast<const float4*>(
        x + ((size_t)bb * L + (valid ? t + LOOKBACK : 0)) * 4);

    const float avw0 = P[WS_AVW + 0], avw1 = P[WS_AVW + 1];
    const float avw2 = P[WS_AVW + 2], avw3 = P[WS_AVW + 3];
    const float cvw  = P[WS_CVW];

    // ---- Phase A: K rows (phi) + V.w_head for rows [t0, t0+NR) ----
    for (int c = tid; c < (NR - 1) * 4; c += TB) {   // 71 rows x 4 chunks = 284
        const int row = c >> 2;
        const int h4  = c & 3;
        const int gl  = t0 + row;
        if (gl >= L) continue;
        const float4 xv = *reinterpret_cast<const float4*>(
            x + ((size_t)bb * L + gl) * 4);

        if (h4 == 0)
            sVW[row] = cvw + xv.x*avw0 + xv.y*avw1 + xv.z*avw2 + xv.w*avw3;

        const int hb = h4 * 8;
        float4 k0 = *reinterpret_cast<const float4*>(P + WS_CK + hb);
        float4 k1 = *reinterpret_cast<const float4*>(P + WS_CK + hb + 4);
#pragma unroll
        for (int d = 0; d < 4; ++d) {
            const float xd = (d == 0) ? xv.x : (d == 1) ? xv.y : (d == 2) ? xv.z : xv.w;
            const float4 a0 = *reinterpret_cast<const float4*>(P + WS_AK + d*HID + hb);
            const float4 a1 = *reinterpret_cast<const float4*>(P + WS_AK + d*HID + hb + 4);
            k0.x += xd*a0.x; k0.y += xd*a0.y; k0.z += xd*a0.z; k0.w += xd*a0.w;
            k1.x += xd*a1.x; k1.y += xd*a1.y; k1.z += xd*a1.z; k1.w += xd*a1.w;
        }
        k0.x = phi1(k0.x); k0.y = phi1(k0.y); k0.z = phi1(k0.z); k0.w = phi1(k0.w);
        k1.x = phi1(k1.x); k1.y = phi1(k1.y); k1.z = phi1(k1.z); k1.w = phi1(k1.w);
        *reinterpret_cast<float4*>(&sK[row * KST + hb])     = k0;
        *reinterpret_cast<float4*>(&sK[row * KST + hb + 4]) = k1;
    }
    __syncthreads();

    // ---- Phase B: 8-channel partial q + partial dots, quad combine ----
    if (!valid) return;

    const int hb = hs * 8;
    float4 q0 = *reinterpret_cast<const float4*>(P + WS_CQ + hb);
    float4 q1 = *reinterpret_cast<const float4*>(P + WS_CQ + hb + 4);
#pragma unroll
    for (int d = 0; d < 4; ++d) {
        const float xd = (d == 0) ? xq.x : (d == 1) ? xq.y : (d == 2) ? xq.z : xq.w;
        const float4 a0 = *reinterpret_cast<const float4*>(P + WS_AQ + d*HID + hb);
        const float4 a1 = *reinterpret_cast<const float4*>(P + WS_AQ + d*HID + hb + 4);
        q0.x += xd*a0.x; q0.y += xd*a0.y; q0.z += xd*a0.z; q0.w += xd*a0.w;
        q1.x += xd*a1.x; q1.y += xd*a1.y; q1.z += xd*a1.z; q1.w += xd*a1.w;
    }
    q0.x = phi1(q0.x); q0.y = phi1(q0.y); q0.z = phi1(q0.z); q0.w = phi1(q0.w);
    q1.x = phi1(q1.x); q1.y = phi1(q1.y); q1.z = phi1(q1.z); q1.w = phi1(q1.w);

    float sc[LOOKBACK];
#pragma unroll
    for (int l = 0; l < LOOKBACK; ++l) {
        const float* kr = &sK[(t_local + l) * KST + hb];
        const float4 k0 = *reinterpret_cast<const float4*>(kr);
        const float4 k1 = *reinterpret_cast<const float4*>(kr + 4);
        sc[l] = q0.x*k0.x + q0.y*k0.y + q0.z*k0.z + q0.w*k0.w
              + q1.x*k1.x + q1.y*k1.y + q1.z*k1.z + q1.w*k1.w;
    }

    // combine partials across the 4-lane quad (DPP quad_perm shuffles)
#pragma unroll
    for (int l = 0; l < LOOKBACK; ++l) {
        sc[l] += __shfl_xor(sc[l], 1, 64);
        sc[l] += __shfl_xor(sc[l], 2, 64);
    }

    float ssum = 0.0f;
#pragma unroll
    for (int l = 0; l < LOOKBACK; ++l) ssum += sc[l];
    const float inv = 1.0f / (ssum + EPS);

    float* wout = out + (size_t)B * T + ((size_t)bb * T + t) * LOOKBACK;
    if (hs == 0) {
        float p = 0.0f;
#pragma unroll
        for (int l = 0; l < LOOKBACK; ++l) p += sc[l] * sVW[t_local + l];
        out[(size_t)bb * T + t] = p * inv + b_head[0];
        *reinterpret_cast<float4*>(wout) =
            make_float4(sc[0]*inv, sc[1]*inv, sc[2]*inv, sc[3]*inv);
    } else if (hs == 1) {
        *reinterpret_cast<float4*>(wout + 4) =
            make_float4(sc[4]*inv, sc[5]*inv, sc[6]*inv, sc[7]*inv);
    }
}

extern "C" void kernel_launch(void* const* d_in, const int* in_sizes, int n_in,
                              void* d_out, int out_size, void* d_ws, size_t ws_size,
                              hipStream_t stream) {
    const float* x  = (const float*)d_in[0];
    const float* sb = (const float*)d_in[1];
    const float* vs = (const float*)d_in[2];
    const float* vb = (const float*)d_in[3];
    const float* bw = (const float*)d_in[4];
    const float* WQ = (const float*)d_in[5];
    const float* WK = (const float*)d_in[6];
    const float* WV = (const float*)d_in[7];
    const float* wh = (const float*)d_in[8];
    const float* bh = (const float*)d_in[9];
    float* out = (float*)d_out;
    float* P   = (float*)d_ws;

    // in_sizes[0] = B*L*4 ; out_size = B*(L-LOOKBACK)*(1+LOOKBACK)
    const long long bl = (long long)in_sizes[0] / 4;            // B*L
    const long long bt = (long long)out_size / (1 + LOOKBACK);  // B*(L-8)
    const int B = (int)((bl - bt) / LOOKBACK);
    const int L = (int)(bl / B);
    const int T = L - LOOKBACK;

    prep_kernel<<<1, 64, 0, stream>>>(sb, vs, vb, bw, WQ, WK, WV, wh, P);

    dim3 grid((T + TPT - 1) / TPT, B);
    ga_main<<<grid, TB, 0, stream>>>(x, P, bh, out, B, L);
}

// Round 4
// 13.335 us; speedup vs baseline: 1.4545x; 1.4545x over previous
//
#include <hip/hip_runtime.h>

#define LOOKBACK 8
#define HID 32
#define TB 256
#define NPOS (TB + LOOKBACK)
#define KST 36          // floats; 144B row stride: 16B-aligned, spreads banks
#define EPS 1e-6f

// sP (LDS) float layout
#define WS_AQ  0     // [4][32]  A_Q
#define WS_CQ  128   // [32]     c_Q
#define WS_AK  160   // [4][32]  A_K
#define WS_CK  288   // [32]     c_K
#define WS_AVW 320   // [4]      a_vw
#define WS_CVW 324   // scalar   c_vw
#define WS_N   336

__device__ __forceinline__ float phi1(float z) {
    return (z >= 0.0f ? z : 0.01f * z) + 1.0f;
}

__global__ __launch_bounds__(TB) void ga_fused(
    const float* __restrict__ x,            // (B, L, 4)
    const float* __restrict__ sbp,          // (1,)
    const float* __restrict__ vsp,          // (4,)
    const float* __restrict__ vbp,          // (4,)
    const float* __restrict__ bwp,          // (6,)
    const float* __restrict__ WQ,           // (11, 32)
    const float* __restrict__ WK,
    const float* __restrict__ WV,
    const float* __restrict__ wh,           // (32,)
    const float* __restrict__ bhp,          // scalar
    float* __restrict__ out,                // pred (B*T) then weights (B*T*8)
    int B, int L)
{
    const int T   = L - LOOKBACK;
    const int bb  = blockIdx.y;
    const int t0  = blockIdx.x * TB;
    const int tid = threadIdx.x;

    __shared__ float sP[WS_N];
    __shared__ float sK[NPOS * KST];
    __shared__ float sVW[NPOS];

    // ---- prefetch this thread's query x (hides under collapse + phase A) ----
    const int t = t0 + tid;
    const bool valid = (t < T);
    const float4 xq = *reinterpret_cast<const float4*>(
        x + ((size_t)bb * L + (valid ? t + LOOKBACK : 0)) * 4);

    // ---- Phase 0: in-block parameter collapse (threads 0..95) ----
    if (tid < 96) {
        const int h   = tid & 31;
        const int mat = tid >> 5;            // 0=Q, 1=K, 2=V
        const float* W = (mat == 0) ? WQ : (mat == 1) ? WK : WV;
        float w[11];
#pragma unroll
        for (int j = 0; j < 11; ++j) w[j] = W[j * HID + h];

        const float b0 = bwp[0], b1 = bwp[1], b2 = bwp[2];
        const float b3 = bwp[3], b4 = bwp[4], b5 = bwp[5];
        const float v0 = vsp[0], v1 = vsp[1], v2 = vsp[2], v3 = vsp[3];
        const float u0 = vbp[0], u1 = vbp[1], u2 = vbp[2], u3 = vbp[3];
        const float s0 = 1.0f + sbp[0];

        // x_d coefficients. BIV_I=[0,0,0,1,1,2], BIV_J=[1,2,3,2,3,3]
        const float a0 = v0*w[1] + b0*w[5] + b1*w[6] + b2*w[7];
        const float a1 = v1*w[2] - b0*w[5] + b3*w[8] + b4*w[9];
        const float a2 = v2*w[3] - b1*w[6] - b3*w[8] + b5*w[10];
        const float a3 = v3*w[4] - b2*w[7] - b4*w[9] - b5*w[10];
        const float c  = s0*w[0] + u0*w[1] + u1*w[2] + u2*w[3] + u3*w[4];

        if (mat == 0) {
            sP[WS_AQ + 0*HID + h] = a0; sP[WS_AQ + 1*HID + h] = a1;
            sP[WS_AQ + 2*HID + h] = a2; sP[WS_AQ + 3*HID + h] = a3;
            sP[WS_CQ + h] = c;
        } else if (mat == 1) {
            sP[WS_AK + 0*HID + h] = a0; sP[WS_AK + 1*HID + h] = a1;
            sP[WS_AK + 2*HID + h] = a2; sP[WS_AK + 3*HID + h] = a3;
            sP[WS_CK + h] = c;
        } else {
            // a_vw[d] = sum_h a_d[h] * wh[h];  c_vw = sum_h c[h] * wh[h]
            const float ww = wh[h];
            float r[5] = { a0*ww, a1*ww, a2*ww, a3*ww, c*ww };
#pragma unroll
            for (int off = 16; off > 0; off >>= 1) {
#pragma unroll
                for (int i = 0; i < 5; ++i) r[i] += __shfl_down(r[i], off, 32);
            }
            if (h == 0) {
                sP[WS_AVW + 0] = r[0]; sP[WS_AVW + 1] = r[1];
                sP[WS_AVW + 2] = r[2]; sP[WS_AVW + 3] = r[3];
                sP[WS_CVW]     = r[4];
            }
        }
    }
    __syncthreads();

    // ---- Phase A: K rows (phi) + V.w_head for positions [t0, t0+npos) ----
    const float avw0 = sP[WS_AVW + 0], avw1 = sP[WS_AVW + 1];
    const float avw2 = sP[WS_AVW + 2], avw3 = sP[WS_AVW + 3];
    const float cvw  = sP[WS_CVW];

    const int npos = min(NPOS, L - t0);
    for (int pos = tid; pos < npos; pos += TB) {
        const float4 xv = *reinterpret_cast<const float4*>(
            x + ((size_t)bb * L + (t0 + pos)) * 4);

        sVW[pos] = cvw + xv.x*avw0 + xv.y*avw1 + xv.z*avw2 + xv.w*avw3;

#pragma unroll
        for (int g = 0; g < 8; ++g) {
            float4 a = *reinterpret_cast<const float4*>(&sP[WS_CK + g*4]);
#pragma unroll
            for (int d = 0; d < 4; ++d) {
                const float xd = (d == 0) ? xv.x : (d == 1) ? xv.y
                               : (d == 2) ? xv.z : xv.w;
                const float4 ad = *reinterpret_cast<const float4*>(
                    &sP[WS_AK + d*HID + g*4]);
                a.x += xd*ad.x; a.y += xd*ad.y; a.z += xd*ad.z; a.w += xd*ad.w;
            }
            a.x = phi1(a.x); a.y = phi1(a.y); a.z = phi1(a.z); a.w = phi1(a.w);
            *reinterpret_cast<float4*>(&sK[pos * KST + g * 4]) = a;
        }
    }
    __syncthreads();

    // ---- Phase B: per-thread q, 8 window dots, outputs ----
    if (!valid) return;

    float q[HID];
#pragma unroll
    for (int g = 0; g < 8; ++g) {
        float4 z = *reinterpret_cast<const float4*>(&sP[WS_CQ + g*4]);
#pragma unroll
        for (int d = 0; d < 4; ++d) {
            const float xd = (d == 0) ? xq.x : (d == 1) ? xq.y
                           : (d == 2) ? xq.z : xq.w;
            const float4 ad = *reinterpret_cast<const float4*>(
                &sP[WS_AQ + d*HID + g*4]);
            z.x += xd*ad.x; z.y += xd*ad.y; z.z += xd*ad.z; z.w += xd*ad.w;
        }
        q[g*4+0] = phi1(z.x); q[g*4+1] = phi1(z.y);
        q[g*4+2] = phi1(z.z); q[g*4+3] = phi1(z.w);
    }

    float sc[LOOKBACK];
#pragma unroll
    for (int l = 0; l < LOOKBACK; ++l) sc[l] = 0.0f;

#pragma unroll
    for (int g = 0; g < 8; ++g) {
        const float qx = q[g*4+0], qy = q[g*4+1], qz = q[g*4+2], qw = q[g*4+3];
#pragma unroll
        for (int l = 0; l < LOOKBACK; ++l) {
            const float4 kg = *reinterpret_cast<const float4*>(
                &sK[(tid + l) * KST + g * 4]);
            sc[l] += qx*kg.x + qy*kg.y + qz*kg.z + qw*kg.w;
        }
    }

    float ssum = 0.0f, p = 0.0f;
#pragma unroll
    for (int l = 0; l < LOOKBACK; ++l) {
        ssum += sc[l];
        p    += sc[l] * sVW[tid + l];
    }
    const float inv = 1.0f / (ssum + EPS);

    out[(size_t)bb * T + t] = p * inv + bhp[0];

    float* wout = out + (size_t)B * T + ((size_t)bb * T + t) * LOOKBACK;
    *reinterpret_cast<float4*>(wout) =
        make_float4(sc[0]*inv, sc[1]*inv, sc[2]*inv, sc[3]*inv);
    *reinterpret_cast<float4*>(wout + 4) =
        make_float4(sc[4]*inv, sc[5]*inv, sc[6]*inv, sc[7]*inv);
}

extern "C" void kernel_launch(void* const* d_in, const int* in_sizes, int n_in,
                              void* d_out, int out_size, void* d_ws, size_t ws_size,
                              hipStream_t stream) {
    const float* x  = (const float*)d_in[0];
    const float* sb = (const float*)d_in[1];
    const float* vs = (const float*)d_in[2];
    const float* vb = (const float*)d_in[3];
    const float* bw = (const float*)d_in[4];
    const float* WQ = (const float*)d_in[5];
    const float* WK = (const float*)d_in[6];
    const float* WV = (const float*)d_in[7];
    const float* wh = (const float*)d_in[8];
    const float* bh = (const float*)d_in[9];
    float* out = (float*)d_out;

    // in_sizes[0] = B*L*4 ; out_size = B*(L-LOOKBACK)*(1+LOOKBACK)
    const long long bl = (long long)in_sizes[0] / 4;            // B*L
    const long long bt = (long long)out_size / (1 + LOOKBACK);  // B*(L-8)
    const int B = (int)((bl - bt) / LOOKBACK);
    const int L = (int)(bl / B);
    const int T = L - LOOKBACK;

    dim3 grid((T + TB - 1) / TB, B);
    ga_fused<<<grid, TB, 0, stream>>>(x, sb, vs, vb, bw, WQ, WK, WV, wh, bh,
                                      out, B, L);
}